// Round 11
// baseline (1465.048 us; speedup 1.0000x reference)
//
#include <hip/hip_runtime.h>

typedef __bf16 bf16_t;
typedef __bf16 bf16x8 __attribute__((ext_vector_type(8)));
typedef __bf16 bf16x4 __attribute__((ext_vector_type(4)));
typedef __bf16 bf16x2 __attribute__((ext_vector_type(2)));
typedef float f32x16 __attribute__((ext_vector_type(16)));
typedef int i32x4 __attribute__((ext_vector_type(4)));

// Problem dims: B=32, S=512, D=512, H=1024, 4H=4096
// ws layout (bytes)
#define SZ_XBF    (16384ull*512*2)      // x bf16, rows permuted to t*32+b
#define SZ_WIH    (4096ull*512*2)
#define SZ_WHH    (4096ull*1024*2)
#define SZ_XPROJ  (16384ull*4096*2)     // [t*32+b][4096] bf16
#define SZ_HTR    (513ull*32*1024*2)    // h trace bf16, slot 0 = h0
#define OFF_XBF   (0ull)
#define OFF_WIH   (OFF_XBF + SZ_XBF)
#define OFF_WHH   (OFF_WIH + SZ_WIH)
#define OFF_XPROJ (OFF_WHH + SZ_WHH)
#define OFF_HTR   (OFF_XPROJ + SZ_XPROJ)

// h trace layout (slab-contiguous per producer, round-4 topology — verified
// optimum; r5-r9 protocol variants all regressed):
//   HTR[t*32768 + slab*512 + b*16 + col]  encodes h_t[b][slab*16 + col]
// Slots 1..512 pre-filled with canary 0xFFFFFFFF (bf16 -NaN pair, impossible
// for finite h). Consumers bulk-load with cache-bypassing loads and retry
// until no canary dword: the DATA is the flag. Fence-free by per-dword store
// atomicity. Lean poll round: issue-16 -> vmcnt(0) -> validate -> branch.
// Round 11 (micro, protocol-neutral):
//  - gL exchange: stride 68 (=4 mod 32) + column bit-shuffle p(c)=(c>>1)|((c&1)<<3)
//    -> write conflict-free, read exactly-2-way (was ~4-way, 8.4M conflict cyc).
//  - canary validate via v_max3_u32: 63 -> 40 VALU ops per round.
//  - OUT store issued BEFORE the poll (ack overlaps poll RTT).
//  - (r10) rcpf-based sigmoid/tanh kept.

// ---------------------------------------------------------------------------
// Kernel 1: convert inputs to bf16 (x permuted), init h-trace slot 0,
//           canary-fill h-trace slots 1..512
// ---------------------------------------------------------------------------
__global__ __launch_bounds__(256) void convert_pack(
    const float* __restrict__ x, const float* __restrict__ h0,
    const float* __restrict__ Wih, const float* __restrict__ Whh,
    bf16_t* __restrict__ xbf, bf16_t* __restrict__ wihbf,
    bf16_t* __restrict__ whhbf, bf16_t* __restrict__ htr)
{
  long long v = (long long)blockIdx.x * 256 + threadIdx.x;
  if (v < 2097152LL) {                       // x: 8388608 floats, 4 per thread
    long long fi = v * 4;
    int b = (int)(fi >> 18);                 // 512*512 = 2^18
    int rem = (int)(fi & 0x3FFFF);
    int s = rem >> 9, d = rem & 511;
    float4 f = *(const float4*)(x + fi);
    bf16x4 o; o.x = (bf16_t)f.x; o.y = (bf16_t)f.y; o.z = (bf16_t)f.z; o.w = (bf16_t)f.w;
    *(bf16x4*)(xbf + ((long long)(s*32 + b)*512 + d)) = o;
  } else if (v < 2621440LL) {                // W_ih: 2097152 floats
    long long fi = (v - 2097152LL) * 4;
    float4 f = *(const float4*)(Wih + fi);
    bf16x4 o; o.x = (bf16_t)f.x; o.y = (bf16_t)f.y; o.z = (bf16_t)f.z; o.w = (bf16_t)f.w;
    *(bf16x4*)(wihbf + fi) = o;
  } else if (v < 3670016LL) {                // W_hh: 4194304 floats
    long long fi = (v - 2621440LL) * 4;
    float4 f = *(const float4*)(Whh + fi);
    bf16x4 o; o.x = (bf16_t)f.x; o.y = (bf16_t)f.y; o.z = (bf16_t)f.z; o.w = (bf16_t)f.w;
    *(bf16x4*)(whhbf + fi) = o;
  } else if (v < 3678208LL) {                // h0: 32768 floats -> htr slot 0 (slab layout)
    long long fi = (v - 3670016LL) * 4;
    int b = (int)(fi >> 10), c = (int)(fi & 1023);
    float4 f = *(const float4*)(h0 + fi);
    bf16x4 o; o.x = (bf16_t)f.x; o.y = (bf16_t)f.y; o.z = (bf16_t)f.z; o.w = (bf16_t)f.w;
    *(bf16x4*)(htr + (long long)(c >> 4) * 512 + b * 16 + (c & 15)) = o;
  } else if (v < 5775360LL) {                // canary fill slots 1..512 (16.78M elems)
    long long idx = v - 3678208LL;           // 2097152 threads * 8 elems
    *(int4*)(htr + 32768LL + idx * 8) = make_int4(-1, -1, -1, -1);
  }
}

// ---------------------------------------------------------------------------
// Kernel 2: x_proj = X(bf16, rows t*32+b) @ W_ih^T + b_ih + b_hh  -> bf16
// ---------------------------------------------------------------------------
__global__ __launch_bounds__(256) void xproj_gemm(
    const bf16_t* __restrict__ Xb, const bf16_t* __restrict__ Wb,
    const float* __restrict__ bih, const float* __restrict__ bhh,
    bf16_t* __restrict__ XP)
{
  __shared__ bf16_t As[128*64];
  __shared__ bf16_t Bs[128*64];
  const int tid = threadIdx.x;
  const int lane = tid & 63, wave = tid >> 6;
  const int mhalf = wave & 1, nhalf = wave >> 1;
  const int l31 = lane & 31, khi = lane >> 5;
  const int m0 = blockIdx.x * 128, n0 = blockIdx.y * 128;

  f32x16 acc[2][2] = {};

  for (int kb = 0; kb < 8; ++kb) {
    const int k0 = kb * 64;
    __syncthreads();
#pragma unroll
    for (int j = 0; j < 4; ++j) {
      int cid = j * 256 + tid;
      int r = cid >> 3, bs = cid & 7;
      int bb = bs ^ (r & 7);
      *(bf16x8*)(As + cid * 8) = *(const bf16x8*)(Xb + (long long)(m0 + r) * 512 + k0 + bb * 8);
      *(bf16x8*)(Bs + cid * 8) = *(const bf16x8*)(Wb + (long long)(n0 + r) * 512 + k0 + bb * 8);
    }
    __syncthreads();
#pragma unroll
    for (int ks = 0; ks < 4; ++ks) {
      int blk = ks * 2 + khi;
      bf16x8 af[2], bfr[2];
#pragma unroll
      for (int mt = 0; mt < 2; ++mt) {
        int r = mhalf * 64 + mt * 32 + l31;
        af[mt] = *(const bf16x8*)(As + (r * 8 + (blk ^ (r & 7))) * 8);
      }
#pragma unroll
      for (int nt = 0; nt < 2; ++nt) {
        int r = nhalf * 64 + nt * 32 + l31;
        bfr[nt] = *(const bf16x8*)(Bs + (r * 8 + (blk ^ (r & 7))) * 8);
      }
#pragma unroll
      for (int mt = 0; mt < 2; ++mt)
#pragma unroll
        for (int nt = 0; nt < 2; ++nt)
          acc[mt][nt] = __builtin_amdgcn_mfma_f32_32x32x16_bf16(af[mt], bfr[nt], acc[mt][nt], 0, 0, 0);
    }
  }
#pragma unroll
  for (int nt = 0; nt < 2; ++nt) {
    int ng = n0 + nhalf * 64 + nt * 32 + l31;
    float bias = bih[ng] + bhh[ng];
#pragma unroll
    for (int mt = 0; mt < 2; ++mt) {
#pragma unroll
      for (int r = 0; r < 16; ++r) {
        int row = (r & 3) + 8 * (r >> 2) + 4 * khi;
        long long mg = m0 + mhalf * 64 + mt * 32 + row;   // = t*32 + b
        XP[mg * 4096 + ng] = (bf16_t)(acc[mt][nt][r] + bias);
      }
    }
  }
}

// ---------------------------------------------------------------------------
// Kernel 3: persistent LSTM recurrence, canary-validated data-poll sync.
// 64 WGs x 256 threads; WG owns 16 h-cols (64 gate rows).
//  - wave = K-quarter: 16 disjoint slabs (16KB), computes BOTH n-tiles.
//  - lean bulk poll with v_max3 validate tree.
//  - gL [parity][4 kq][32 m][68] bit-shuffled columns -> 2-way-max banks.
//  - c in regs; OUT deferred one step and stored BEFORE the poll.
// ---------------------------------------------------------------------------
__device__ __forceinline__ float sigf(float x) {
  return __builtin_amdgcn_rcpf(1.0f + __expf(-x));
}
__device__ __forceinline__ float tanhfast(float x) {
  float e = __expf(-2.0f * fabsf(x));
  float t = (1.0f - e) * __builtin_amdgcn_rcpf(1.0f + e);
  return copysignf(t, x);
}
__device__ __forceinline__ unsigned umax2(unsigned a, unsigned b) { return a > b ? a : b; }
__device__ __forceinline__ unsigned umax3(unsigned a, unsigned b, unsigned c) {
  unsigned d;
  asm("v_max3_u32 %0, %1, %2, %3" : "=v"(d) : "v"(a), "v"(b), "v"(c));
  return d;
}

#define LD16(dst, ptr, OFF) \
  asm volatile("global_load_dwordx4 %0, %1, off offset:" OFF " sc0 sc1" \
               : "=v"(dst) : "v"(ptr) : "memory")

__global__ __launch_bounds__(256, 1) void lstm_rec(
    const bf16_t* __restrict__ Whh_b, const bf16_t* __restrict__ XP,
    const float* __restrict__ c0, float* __restrict__ OUT,
    bf16_t* __restrict__ HTR)
{
  const int tid = threadIdx.x;
  const int lane = tid & 63, wave = tid >> 6;
  const int kq = wave;                              // K-quarter 0..3
  const int wg = blockIdx.x;
  const int l31 = lane & 31, khi = lane >> 5;

  // --- preload W_hh fragments for BOTH n-tiles of my K-quarter ---
  const int g0row = (l31 >> 4) * 1024 + wg * 16 + (l31 & 15);
  const int g1row = (2 + (l31 >> 4)) * 1024 + wg * 16 + (l31 & 15);
  const int kqb = kq * 256 + khi * 8;               // k-base of my quarter
  bf16x8 w0[16], w1[16];
#pragma unroll
  for (int s = 0; s < 16; ++s) {
    w0[s] = *(const bf16x8*)(Whh_b + (long long)g0row * 1024 + kqb + s * 16);
    w1[s] = *(const bf16x8*)(Whh_b + (long long)g1row * 1024 + kqb + s * 16);
  }

  // A-fragment byte base: slab (kq*16+s), row l31, cols khi*8..+8
  const char* abase = (const char*)HTR + kq * 16384 + l31 * 32 + khi * 16;

  // gate exchange LDS: [parity][kq][m][68], stride 68 (=4 mod 32 banks).
  // Physical column = 16*gate + p(c16), p(c) = (c>>1) | ((c&1)<<3):
  //   write banks 4*mm + perm(0..31)  -> conflict-free
  //   read  banks 4*m' + j + const    -> exactly 2-way (free)
  __shared__ float gLb[2][4][32][68];
  // write-side physical column (per thread, const):
  const int colw = ((l31 >> 4) << 4) | (((l31 & 15) >> 1) | ((l31 & 1) << 3));

  const int m_e = tid >> 3;
  const int jp = (tid & 7) * 2;          // logical col pair (jp, jp+1)
  const int jA = tid & 7;                // physical col of jp   (e=0)
  const int jB = jA + 8;                 // physical col of jp+1 (e=1)
  float cr0 = c0[m_e * 1024 + wg * 16 + jp];
  float cr1 = c0[m_e * 1024 + wg * 16 + jp + 1];

  // prefetch xp for t=0
  float xp[4][2];
  {
    const bf16_t* xpb = XP + (long long)m_e * 4096 + wg * 16 + jp;
#pragma unroll
    for (int g = 0; g < 4; ++g) {
      bf16x2 v = *(const bf16x2*)(xpb + g * 1024);
      xp[g][0] = (float)v.x; xp[g][1] = (float)v.y;
    }
  }

  float po0 = 0.0f, po1 = 0.0f;   // deferred OUT values (step t-1)

  for (int t = 0; t < 512; ++t) {
    // ---- deferred OUT store for step t-1 (issue BEFORE poll; ack overlaps) ----
    if (t > 0)
      *(float2*)(OUT + ((long long)m_e * 512 + (t - 1)) * 1024 + wg * 16 + jp) =
          make_float2(po0, po1);

    // ---- bulk-load + canary-validate the 16 slabs of my K-quarter ----
    const char* p0 = abase + ((long long)t << 16);
    const char* p1 = p0 + 4096;
    const char* p2 = p0 + 8192;
    const char* p3 = p0 + 12288;
    i32x4 a[16];
    for (;;) {
      LD16(a[0],  p0, "0"); LD16(a[1],  p0, "1024"); LD16(a[2],  p0, "2048"); LD16(a[3],  p0, "3072");
      LD16(a[4],  p1, "0"); LD16(a[5],  p1, "1024"); LD16(a[6],  p1, "2048"); LD16(a[7],  p1, "3072");
      LD16(a[8],  p2, "0"); LD16(a[9],  p2, "1024"); LD16(a[10], p2, "2048"); LD16(a[11], p2, "3072");
      LD16(a[12], p3, "0"); LD16(a[13], p3, "1024"); LD16(a[14], p3, "2048"); LD16(a[15], p3, "3072");
      asm volatile("s_waitcnt vmcnt(0)" ::: "memory");
      __builtin_amdgcn_sched_barrier(0);
      // v_max3 tree: 16x2 + 5 + 2 + 1 = 40 ops (was 63)
      unsigned pv[16];
#pragma unroll
      for (int s = 0; s < 16; ++s)
        pv[s] = umax2(umax3((unsigned)a[s][0], (unsigned)a[s][1],
                            (unsigned)a[s][2]), (unsigned)a[s][3]);
      unsigned q0 = umax3(pv[0],  pv[1],  pv[2]);
      unsigned q1 = umax3(pv[3],  pv[4],  pv[5]);
      unsigned q2 = umax3(pv[6],  pv[7],  pv[8]);
      unsigned q3 = umax3(pv[9],  pv[10], pv[11]);
      unsigned q4 = umax3(pv[12], pv[13], pv[14]);
      unsigned r0 = umax3(q0, q1, q2);
      unsigned r1 = umax3(q3, q4, pv[15]);
      unsigned mx = umax2(r0, r1);
      if (!__any((int)(mx == 0xFFFFFFFFu))) break;
    }

    // ---- gates partial for my K-quarter, both n-tiles ----
    f32x16 acc0 = {}, acc1 = {};
#pragma unroll
    for (int s = 0; s < 16; ++s) {
      bf16x8 af = __builtin_bit_cast(bf16x8, a[s]);
      acc0 = __builtin_amdgcn_mfma_f32_32x32x16_bf16(af, w0[s], acc0, 0, 0, 0);
      acc1 = __builtin_amdgcn_mfma_f32_32x32x16_bf16(af, w1[s], acc1, 0, 0, 0);
    }

    float (*gp)[68] = gLb[t & 1][kq];
#pragma unroll
    for (int r = 0; r < 16; ++r) {
      int mm = (r & 3) + 8 * (r >> 2) + 4 * khi;
      gp[mm][colw]      = acc0[r];
      gp[mm][colw + 32] = acc1[r];
    }
    __syncthreads();   // single barrier per step (gL parity-double-buffered)

    // ---- elementwise LSTM cell for (m_e, jp..jp+1), c in registers ----
    float (*ge)[32][68] = gLb[t & 1];
    float hv[2];
    {
      float ir  = ge[0][m_e][jA]      + ge[1][m_e][jA]      + ge[2][m_e][jA]      + ge[3][m_e][jA]      + xp[0][0];
      float fr  = ge[0][m_e][16 + jA] + ge[1][m_e][16 + jA] + ge[2][m_e][16 + jA] + ge[3][m_e][16 + jA] + xp[1][0];
      float gr  = ge[0][m_e][32 + jA] + ge[1][m_e][32 + jA] + ge[2][m_e][32 + jA] + ge[3][m_e][32 + jA] + xp[2][0];
      float orr = ge[0][m_e][48 + jA] + ge[1][m_e][48 + jA] + ge[2][m_e][48 + jA] + ge[3][m_e][48 + jA] + xp[3][0];
      float c = sigf(fr) * cr0 + sigf(ir) * tanhfast(gr);
      cr0 = c;
      hv[0] = sigf(orr) * tanhfast(c);
    }
    {
      float ir  = ge[0][m_e][jB]      + ge[1][m_e][jB]      + ge[2][m_e][jB]      + ge[3][m_e][jB]      + xp[0][1];
      float fr  = ge[0][m_e][16 + jB] + ge[1][m_e][16 + jB] + ge[2][m_e][16 + jB] + ge[3][m_e][16 + jB] + xp[1][1];
      float gr  = ge[0][m_e][32 + jB] + ge[1][m_e][32 + jB] + ge[2][m_e][32 + jB] + ge[3][m_e][32 + jB] + xp[2][1];
      float orr = ge[0][m_e][48 + jB] + ge[1][m_e][48 + jB] + ge[2][m_e][48 + jB] + ge[3][m_e][48 + jB] + xp[3][1];
      float c = sigf(fr) * cr1 + sigf(ir) * tanhfast(gr);
      cr1 = c;
      hv[1] = sigf(orr) * tanhfast(c);
    }

    // ---- publish h: sc1 store to LLC, fire-and-forget (data IS the flag) ----
    {
      bf16x2 h2; h2.x = (bf16_t)hv[0]; h2.y = (bf16_t)hv[1];
      unsigned int u = __builtin_bit_cast(unsigned int, h2);
      unsigned int* dst = (unsigned int*)(HTR + (long long)(t + 1) * 32768 +
                                          (long long)wg * 512 + m_e * 16 + jp);
      __hip_atomic_store(dst, u, __ATOMIC_RELAXED, __HIP_MEMORY_SCOPE_AGENT);
    }
    po0 = hv[0]; po1 = hv[1];

    // ---- next-step xp prefetch ----
    if (t < 511) {
      const bf16_t* xpb = XP + ((long long)(t + 1) * 32 + m_e) * 4096 + wg * 16 + jp;
#pragma unroll
      for (int g = 0; g < 4; ++g) {
        bf16x2 v = *(const bf16x2*)(xpb + g * 1024);
        xp[g][0] = (float)v.x; xp[g][1] = (float)v.y;
      }
    }
  }
  // final OUT store (t = 511)
  *(float2*)(OUT + ((long long)m_e * 512 + 511) * 1024 + wg * 16 + jp) =
      make_float2(po0, po1);
}

// ---------------------------------------------------------------------------
extern "C" void kernel_launch(void* const* d_in, const int* in_sizes, int n_in,
                              void* d_out, int out_size, void* d_ws, size_t ws_size,
                              hipStream_t stream)
{
  const float* x   = (const float*)d_in[0];
  const float* h0  = (const float*)d_in[1];
  const float* c0  = (const float*)d_in[2];
  const float* Wih = (const float*)d_in[3];
  const float* Whh = (const float*)d_in[4];
  const float* bih = (const float*)d_in[5];
  const float* bhh = (const float*)d_in[6];
  float* out = (float*)d_out;

  char* ws = (char*)d_ws;
  bf16_t* xbf   = (bf16_t*)(ws + OFF_XBF);
  bf16_t* wihbf = (bf16_t*)(ws + OFF_WIH);
  bf16_t* whhbf = (bf16_t*)(ws + OFF_WHH);
  bf16_t* xproj = (bf16_t*)(ws + OFF_XPROJ);
  bf16_t* htr   = (bf16_t*)(ws + OFF_HTR);

  convert_pack<<<22560, 256, 0, stream>>>(x, h0, Wih, Whh, xbf, wihbf, whhbf, htr);
  xproj_gemm<<<dim3(128, 32), 256, 0, stream>>>(xbf, wihbf, bih, bhh, xproj);
  lstm_rec<<<64, 256, 0, stream>>>(whhbf, xproj, c0, out, htr);
}

// Round 12
// 1455.647 us; speedup vs baseline: 1.0065x; 1.0065x over previous
//
#include <hip/hip_runtime.h>

typedef __bf16 bf16_t;
typedef __bf16 bf16x8 __attribute__((ext_vector_type(8)));
typedef __bf16 bf16x4 __attribute__((ext_vector_type(4)));
typedef __bf16 bf16x2 __attribute__((ext_vector_type(2)));
typedef float f32x16 __attribute__((ext_vector_type(16)));
typedef int i32x4 __attribute__((ext_vector_type(4)));

// Problem dims: B=32, S=512, D=512, H=1024, 4H=4096
// ws layout (bytes)
#define SZ_XBF    (16384ull*512*2)      // x bf16, rows permuted to t*32+b
#define SZ_WIH    (4096ull*512*2)
#define SZ_WHH    (4096ull*1024*2)
#define SZ_XPROJ  (16384ull*4096*2)     // [t*32+b][4096] bf16
#define SZ_HTR    (513ull*32*1024*2)    // h trace bf16, slot 0 = h0
#define OFF_XBF   (0ull)
#define OFF_WIH   (OFF_XBF + SZ_XBF)
#define OFF_WHH   (OFF_WIH + SZ_WIH)
#define OFF_XPROJ (OFF_WHH + SZ_WHH)
#define OFF_HTR   (OFF_XPROJ + SZ_XPROJ)

// h trace layout (slab-contiguous per producer, round-4 topology — verified
// optimum; r5-r9 protocol variants all regressed):
//   HTR[t*32768 + slab*512 + b*16 + col]  encodes h_t[b][slab*16 + col]
// Slots 1..512 pre-filled with canary 0xFFFFFFFF (bf16 -NaN pair, impossible
// for finite h). Consumers bulk-load with cache-bypassing loads and retry
// until no canary dword: the DATA is the flag. Fence-free by per-dword store
// atomicity. Lean poll round: issue-16 -> vmcnt(0) -> validate -> branch.
// Round 12 (serial-tail + storm, protocol-neutral):
//  - gL exchange packed as float2 (i,g)/(f,o): 16 ds_write_b64 + 16
//    ds_read_b64 per thread (was 32+32 b32) -> ~halves LDS time on the
//    detect->publish serial chain.
//  - s_sleep(1) backoff on poll-FAILURE path only: thins the 4MB re-issue
//    storm that inflates the succeeding round's RTT; zero cost on success.
//  - (r10) rcpf sigmoid/tanh, (r11) v_max3 validate + OUT-before-poll kept.

// ---------------------------------------------------------------------------
// Kernel 1: convert inputs to bf16 (x permuted), init h-trace slot 0,
//           canary-fill h-trace slots 1..512
// ---------------------------------------------------------------------------
__global__ __launch_bounds__(256) void convert_pack(
    const float* __restrict__ x, const float* __restrict__ h0,
    const float* __restrict__ Wih, const float* __restrict__ Whh,
    bf16_t* __restrict__ xbf, bf16_t* __restrict__ wihbf,
    bf16_t* __restrict__ whhbf, bf16_t* __restrict__ htr)
{
  long long v = (long long)blockIdx.x * 256 + threadIdx.x;
  if (v < 2097152LL) {                       // x: 8388608 floats, 4 per thread
    long long fi = v * 4;
    int b = (int)(fi >> 18);                 // 512*512 = 2^18
    int rem = (int)(fi & 0x3FFFF);
    int s = rem >> 9, d = rem & 511;
    float4 f = *(const float4*)(x + fi);
    bf16x4 o; o.x = (bf16_t)f.x; o.y = (bf16_t)f.y; o.z = (bf16_t)f.z; o.w = (bf16_t)f.w;
    *(bf16x4*)(xbf + ((long long)(s*32 + b)*512 + d)) = o;
  } else if (v < 2621440LL) {                // W_ih: 2097152 floats
    long long fi = (v - 2097152LL) * 4;
    float4 f = *(const float4*)(Wih + fi);
    bf16x4 o; o.x = (bf16_t)f.x; o.y = (bf16_t)f.y; o.z = (bf16_t)f.z; o.w = (bf16_t)f.w;
    *(bf16x4*)(wihbf + fi) = o;
  } else if (v < 3670016LL) {                // W_hh: 4194304 floats
    long long fi = (v - 2621440LL) * 4;
    float4 f = *(const float4*)(Whh + fi);
    bf16x4 o; o.x = (bf16_t)f.x; o.y = (bf16_t)f.y; o.z = (bf16_t)f.z; o.w = (bf16_t)f.w;
    *(bf16x4*)(whhbf + fi) = o;
  } else if (v < 3678208LL) {                // h0: 32768 floats -> htr slot 0 (slab layout)
    long long fi = (v - 3670016LL) * 4;
    int b = (int)(fi >> 10), c = (int)(fi & 1023);
    float4 f = *(const float4*)(h0 + fi);
    bf16x4 o; o.x = (bf16_t)f.x; o.y = (bf16_t)f.y; o.z = (bf16_t)f.z; o.w = (bf16_t)f.w;
    *(bf16x4*)(htr + (long long)(c >> 4) * 512 + b * 16 + (c & 15)) = o;
  } else if (v < 5775360LL) {                // canary fill slots 1..512 (16.78M elems)
    long long idx = v - 3678208LL;           // 2097152 threads * 8 elems
    *(int4*)(htr + 32768LL + idx * 8) = make_int4(-1, -1, -1, -1);
  }
}

// ---------------------------------------------------------------------------
// Kernel 2: x_proj = X(bf16, rows t*32+b) @ W_ih^T + b_ih + b_hh  -> bf16
// ---------------------------------------------------------------------------
__global__ __launch_bounds__(256) void xproj_gemm(
    const bf16_t* __restrict__ Xb, const bf16_t* __restrict__ Wb,
    const float* __restrict__ bih, const float* __restrict__ bhh,
    bf16_t* __restrict__ XP)
{
  __shared__ bf16_t As[128*64];
  __shared__ bf16_t Bs[128*64];
  const int tid = threadIdx.x;
  const int lane = tid & 63, wave = tid >> 6;
  const int mhalf = wave & 1, nhalf = wave >> 1;
  const int l31 = lane & 31, khi = lane >> 5;
  const int m0 = blockIdx.x * 128, n0 = blockIdx.y * 128;

  f32x16 acc[2][2] = {};

  for (int kb = 0; kb < 8; ++kb) {
    const int k0 = kb * 64;
    __syncthreads();
#pragma unroll
    for (int j = 0; j < 4; ++j) {
      int cid = j * 256 + tid;
      int r = cid >> 3, bs = cid & 7;
      int bb = bs ^ (r & 7);
      *(bf16x8*)(As + cid * 8) = *(const bf16x8*)(Xb + (long long)(m0 + r) * 512 + k0 + bb * 8);
      *(bf16x8*)(Bs + cid * 8) = *(const bf16x8*)(Wb + (long long)(n0 + r) * 512 + k0 + bb * 8);
    }
    __syncthreads();
#pragma unroll
    for (int ks = 0; ks < 4; ++ks) {
      int blk = ks * 2 + khi;
      bf16x8 af[2], bfr[2];
#pragma unroll
      for (int mt = 0; mt < 2; ++mt) {
        int r = mhalf * 64 + mt * 32 + l31;
        af[mt] = *(const bf16x8*)(As + (r * 8 + (blk ^ (r & 7))) * 8);
      }
#pragma unroll
      for (int nt = 0; nt < 2; ++nt) {
        int r = nhalf * 64 + nt * 32 + l31;
        bfr[nt] = *(const bf16x8*)(Bs + (r * 8 + (blk ^ (r & 7))) * 8);
      }
#pragma unroll
      for (int mt = 0; mt < 2; ++mt)
#pragma unroll
        for (int nt = 0; nt < 2; ++nt)
          acc[mt][nt] = __builtin_amdgcn_mfma_f32_32x32x16_bf16(af[mt], bfr[nt], acc[mt][nt], 0, 0, 0);
    }
  }
#pragma unroll
  for (int nt = 0; nt < 2; ++nt) {
    int ng = n0 + nhalf * 64 + nt * 32 + l31;
    float bias = bih[ng] + bhh[ng];
#pragma unroll
    for (int mt = 0; mt < 2; ++mt) {
#pragma unroll
      for (int r = 0; r < 16; ++r) {
        int row = (r & 3) + 8 * (r >> 2) + 4 * khi;
        long long mg = m0 + mhalf * 64 + mt * 32 + row;   // = t*32 + b
        XP[mg * 4096 + ng] = (bf16_t)(acc[mt][nt][r] + bias);
      }
    }
  }
}

// ---------------------------------------------------------------------------
// Kernel 3: persistent LSTM recurrence, canary-validated data-poll sync.
// 64 WGs x 256 threads; WG owns 16 h-cols (64 gate rows).
//  - wave = K-quarter: 16 disjoint slabs (16KB), computes BOTH n-tiles.
//  - lean bulk poll + v_max3 validate + s_sleep(1) failure backoff.
//  - gL exchange as float2 pairs (i,g)/(f,o): 16 b64 writes + 16 b64 reads.
//  - c in regs; OUT deferred one step and stored BEFORE the poll.
// ---------------------------------------------------------------------------
__device__ __forceinline__ float sigf(float x) {
  return __builtin_amdgcn_rcpf(1.0f + __expf(-x));
}
__device__ __forceinline__ float tanhfast(float x) {
  float e = __expf(-2.0f * fabsf(x));
  float t = (1.0f - e) * __builtin_amdgcn_rcpf(1.0f + e);
  return copysignf(t, x);
}
__device__ __forceinline__ unsigned umax2(unsigned a, unsigned b) { return a > b ? a : b; }
__device__ __forceinline__ unsigned umax3(unsigned a, unsigned b, unsigned c) {
  unsigned d;
  asm("v_max3_u32 %0, %1, %2, %3" : "=v"(d) : "v"(a), "v"(b), "v"(c));
  return d;
}

#define LD16(dst, ptr, OFF) \
  asm volatile("global_load_dwordx4 %0, %1, off offset:" OFF " sc0 sc1" \
               : "=v"(dst) : "v"(ptr) : "memory")

__global__ __launch_bounds__(256, 1) void lstm_rec(
    const bf16_t* __restrict__ Whh_b, const bf16_t* __restrict__ XP,
    const float* __restrict__ c0, float* __restrict__ OUT,
    bf16_t* __restrict__ HTR)
{
  const int tid = threadIdx.x;
  const int lane = tid & 63, wave = tid >> 6;
  const int kq = wave;                              // K-quarter 0..3
  const int wg = blockIdx.x;
  const int l31 = lane & 31, khi = lane >> 5;

  // --- preload W_hh fragments for BOTH n-tiles of my K-quarter ---
  const int g0row = (l31 >> 4) * 1024 + wg * 16 + (l31 & 15);
  const int g1row = (2 + (l31 >> 4)) * 1024 + wg * 16 + (l31 & 15);
  const int kqb = kq * 256 + khi * 8;               // k-base of my quarter
  bf16x8 w0[16], w1[16];
#pragma unroll
  for (int s = 0; s < 16; ++s) {
    w0[s] = *(const bf16x8*)(Whh_b + (long long)g0row * 1024 + kqb + s * 16);
    w1[s] = *(const bf16x8*)(Whh_b + (long long)g1row * 1024 + kqb + s * 16);
  }

  // A-fragment byte base: slab (kq*16+s), row l31, cols khi*8..+8
  const char* abase = (const char*)HTR + kq * 16384 + l31 * 32 + khi * 16;

  // gate exchange LDS, float2-packed: gL2[parity][kq][m][col] where
  //   col<16: (i_c, g_c), col>=16: (f_{c-16}, o_{c-16})
  __shared__ float2 gL2[2][4][32][33];   // 33-pad, 67.6KB total

  const int m_e = tid >> 3;
  const int jp = (tid & 7) * 2;          // owned col pair (jp, jp+1), 0..14
  float cr0 = c0[m_e * 1024 + wg * 16 + jp];
  float cr1 = c0[m_e * 1024 + wg * 16 + jp + 1];

  // prefetch xp for t=0
  float xp[4][2];
  {
    const bf16_t* xpb = XP + (long long)m_e * 4096 + wg * 16 + jp;
#pragma unroll
    for (int g = 0; g < 4; ++g) {
      bf16x2 v = *(const bf16x2*)(xpb + g * 1024);
      xp[g][0] = (float)v.x; xp[g][1] = (float)v.y;
    }
  }

  float po0 = 0.0f, po1 = 0.0f;   // deferred OUT values (step t-1)

  for (int t = 0; t < 512; ++t) {
    // ---- deferred OUT store for step t-1 (issue BEFORE poll; ack overlaps) ----
    if (t > 0)
      *(float2*)(OUT + ((long long)m_e * 512 + (t - 1)) * 1024 + wg * 16 + jp) =
          make_float2(po0, po1);

    // ---- bulk-load + canary-validate the 16 slabs of my K-quarter ----
    const char* p0 = abase + ((long long)t << 16);
    const char* p1 = p0 + 4096;
    const char* p2 = p0 + 8192;
    const char* p3 = p0 + 12288;
    i32x4 a[16];
    for (;;) {
      LD16(a[0],  p0, "0"); LD16(a[1],  p0, "1024"); LD16(a[2],  p0, "2048"); LD16(a[3],  p0, "3072");
      LD16(a[4],  p1, "0"); LD16(a[5],  p1, "1024"); LD16(a[6],  p1, "2048"); LD16(a[7],  p1, "3072");
      LD16(a[8],  p2, "0"); LD16(a[9],  p2, "1024"); LD16(a[10], p2, "2048"); LD16(a[11], p2, "3072");
      LD16(a[12], p3, "0"); LD16(a[13], p3, "1024"); LD16(a[14], p3, "2048"); LD16(a[15], p3, "3072");
      asm volatile("s_waitcnt vmcnt(0)" ::: "memory");
      __builtin_amdgcn_sched_barrier(0);
      // v_max3 tree: 40 ops
      unsigned pv[16];
#pragma unroll
      for (int s = 0; s < 16; ++s)
        pv[s] = umax2(umax3((unsigned)a[s][0], (unsigned)a[s][1],
                            (unsigned)a[s][2]), (unsigned)a[s][3]);
      unsigned q0 = umax3(pv[0],  pv[1],  pv[2]);
      unsigned q1 = umax3(pv[3],  pv[4],  pv[5]);
      unsigned q2 = umax3(pv[6],  pv[7],  pv[8]);
      unsigned q3 = umax3(pv[9],  pv[10], pv[11]);
      unsigned q4 = umax3(pv[12], pv[13], pv[14]);
      unsigned r0 = umax3(q0, q1, q2);
      unsigned r1 = umax3(q3, q4, pv[15]);
      unsigned mx = umax2(r0, r1);
      if (!__any((int)(mx == 0xFFFFFFFFu))) break;
      __builtin_amdgcn_s_sleep(1);   // failure path only: thin the re-issue storm
    }

    // ---- gates partial for my K-quarter, both n-tiles ----
    f32x16 acc0 = {}, acc1 = {};
#pragma unroll
    for (int s = 0; s < 16; ++s) {
      bf16x8 af = __builtin_bit_cast(bf16x8, a[s]);
      acc0 = __builtin_amdgcn_mfma_f32_32x32x16_bf16(af, w0[s], acc0, 0, 0, 0);
      acc1 = __builtin_amdgcn_mfma_f32_32x32x16_bf16(af, w1[s], acc1, 0, 0, 0);
    }

    float2 (*gp)[33] = gL2[t & 1][kq];
#pragma unroll
    for (int r = 0; r < 16; ++r) {
      int mm = (r & 3) + 8 * (r >> 2) + 4 * khi;
      gp[mm][l31] = make_float2(acc0[r], acc1[r]);   // (i|f, g|o) pair
    }
    __syncthreads();   // single barrier per step (gL parity-double-buffered)

    // ---- elementwise LSTM cell for (m_e, jp..jp+1), c in registers ----
    float2 (*ge)[32][33] = gL2[t & 1];
    float hv[2];
    {
      float ir = xp[0][0], fr = xp[1][0], gr = xp[2][0], orr = xp[3][0];
#pragma unroll
      for (int k = 0; k < 4; ++k) {
        float2 ig = ge[k][m_e][jp];
        float2 fo = ge[k][m_e][16 + jp];
        ir += ig.x; gr += ig.y; fr += fo.x; orr += fo.y;
      }
      float c = sigf(fr) * cr0 + sigf(ir) * tanhfast(gr);
      cr0 = c;
      hv[0] = sigf(orr) * tanhfast(c);
    }
    {
      float ir = xp[0][1], fr = xp[1][1], gr = xp[2][1], orr = xp[3][1];
#pragma unroll
      for (int k = 0; k < 4; ++k) {
        float2 ig = ge[k][m_e][jp + 1];
        float2 fo = ge[k][m_e][17 + jp];
        ir += ig.x; gr += ig.y; fr += fo.x; orr += fo.y;
      }
      float c = sigf(fr) * cr1 + sigf(ir) * tanhfast(gr);
      cr1 = c;
      hv[1] = sigf(orr) * tanhfast(c);
    }

    // ---- publish h: sc1 store to LLC, fire-and-forget (data IS the flag) ----
    {
      bf16x2 h2; h2.x = (bf16_t)hv[0]; h2.y = (bf16_t)hv[1];
      unsigned int u = __builtin_bit_cast(unsigned int, h2);
      unsigned int* dst = (unsigned int*)(HTR + (long long)(t + 1) * 32768 +
                                          (long long)wg * 512 + m_e * 16 + jp);
      __hip_atomic_store(dst, u, __ATOMIC_RELAXED, __HIP_MEMORY_SCOPE_AGENT);
    }
    po0 = hv[0]; po1 = hv[1];

    // ---- next-step xp prefetch ----
    if (t < 511) {
      const bf16_t* xpb = XP + ((long long)(t + 1) * 32 + m_e) * 4096 + wg * 16 + jp;
#pragma unroll
      for (int g = 0; g < 4; ++g) {
        bf16x2 v = *(const bf16x2*)(xpb + g * 1024);
        xp[g][0] = (float)v.x; xp[g][1] = (float)v.y;
      }
    }
  }
  // final OUT store (t = 511)
  *(float2*)(OUT + ((long long)m_e * 512 + 511) * 1024 + wg * 16 + jp) =
      make_float2(po0, po1);
}

// ---------------------------------------------------------------------------
extern "C" void kernel_launch(void* const* d_in, const int* in_sizes, int n_in,
                              void* d_out, int out_size, void* d_ws, size_t ws_size,
                              hipStream_t stream)
{
  const float* x   = (const float*)d_in[0];
  const float* h0  = (const float*)d_in[1];
  const float* c0  = (const float*)d_in[2];
  const float* Wih = (const float*)d_in[3];
  const float* Whh = (const float*)d_in[4];
  const float* bih = (const float*)d_in[5];
  const float* bhh = (const float*)d_in[6];
  float* out = (float*)d_out;

  char* ws = (char*)d_ws;
  bf16_t* xbf   = (bf16_t*)(ws + OFF_XBF);
  bf16_t* wihbf = (bf16_t*)(ws + OFF_WIH);
  bf16_t* whhbf = (bf16_t*)(ws + OFF_WHH);
  bf16_t* xproj = (bf16_t*)(ws + OFF_XPROJ);
  bf16_t* htr   = (bf16_t*)(ws + OFF_HTR);

  convert_pack<<<22560, 256, 0, stream>>>(x, h0, Wih, Whh, xbf, wihbf, whhbf, htr);
  xproj_gemm<<<dim3(128, 32), 256, 0, stream>>>(xbf, wihbf, bih, bhh, xproj);
  lstm_rec<<<64, 256, 0, stream>>>(whhbf, xproj, c0, out, htr);
}

// Round 13
// 1446.571 us; speedup vs baseline: 1.0128x; 1.0063x over previous
//
#include <hip/hip_runtime.h>

typedef __bf16 bf16_t;
typedef __bf16 bf16x8 __attribute__((ext_vector_type(8)));
typedef __bf16 bf16x4 __attribute__((ext_vector_type(4)));
typedef __bf16 bf16x2 __attribute__((ext_vector_type(2)));
typedef float f32x16 __attribute__((ext_vector_type(16)));
typedef int i32x4 __attribute__((ext_vector_type(4)));

// Problem dims: B=32, S=512, D=512, H=1024, 4H=4096
// ws layout (bytes)
#define SZ_XBF    (16384ull*512*2)      // x bf16, rows permuted to t*32+b
#define SZ_WIH    (4096ull*512*2)
#define SZ_WHH    (4096ull*1024*2)
#define SZ_XPROJ  (16384ull*4096*2)     // [t*32+b][4096] bf16
#define SZ_HTR    (513ull*32*1024*2)    // h trace bf16, slot 0 = h0
#define OFF_XBF   (0ull)
#define OFF_WIH   (OFF_XBF + SZ_XBF)
#define OFF_WHH   (OFF_WIH + SZ_WIH)
#define OFF_XPROJ (OFF_WHH + SZ_WHH)
#define OFF_HTR   (OFF_XPROJ + SZ_XPROJ)

// h trace layout (slab-contiguous per producer, round-4 topology — verified
// optimum; r5-r9 protocol variants all regressed):
//   HTR[t*32768 + slab*512 + b*16 + col]  encodes h_t[b][slab*16 + col]
// Slots 1..512 pre-filled with canary 0xFFFFFFFF (bf16 -NaN pair, impossible
// for finite h). Consumers bulk-load with cache-bypassing loads and retry
// until no canary dword: the DATA is the flag. Fence-free by per-dword store
// atomicity. lstm_rec is at its protocol latency floor (~2.46us/step,
// r10-r12); FROZEN as of r12.
// Round 13: xproj_gemm upgraded with global_load_lds width-16 (m97 ladder
// step): staging was already pre-swizzled-source + linear-LDS-dest, so the
// async direct-to-LDS form drops the VGPR round-trip + addr-calc VALU.

// ---------------------------------------------------------------------------
// Kernel 1: convert inputs to bf16 (x permuted), init h-trace slot 0,
//           canary-fill h-trace slots 1..512
// ---------------------------------------------------------------------------
__global__ __launch_bounds__(256) void convert_pack(
    const float* __restrict__ x, const float* __restrict__ h0,
    const float* __restrict__ Wih, const float* __restrict__ Whh,
    bf16_t* __restrict__ xbf, bf16_t* __restrict__ wihbf,
    bf16_t* __restrict__ whhbf, bf16_t* __restrict__ htr)
{
  long long v = (long long)blockIdx.x * 256 + threadIdx.x;
  if (v < 2097152LL) {                       // x: 8388608 floats, 4 per thread
    long long fi = v * 4;
    int b = (int)(fi >> 18);                 // 512*512 = 2^18
    int rem = (int)(fi & 0x3FFFF);
    int s = rem >> 9, d = rem & 511;
    float4 f = *(const float4*)(x + fi);
    bf16x4 o; o.x = (bf16_t)f.x; o.y = (bf16_t)f.y; o.z = (bf16_t)f.z; o.w = (bf16_t)f.w;
    *(bf16x4*)(xbf + ((long long)(s*32 + b)*512 + d)) = o;
  } else if (v < 2621440LL) {                // W_ih: 2097152 floats
    long long fi = (v - 2097152LL) * 4;
    float4 f = *(const float4*)(Wih + fi);
    bf16x4 o; o.x = (bf16_t)f.x; o.y = (bf16_t)f.y; o.z = (bf16_t)f.z; o.w = (bf16_t)f.w;
    *(bf16x4*)(wihbf + fi) = o;
  } else if (v < 3670016LL) {                // W_hh: 4194304 floats
    long long fi = (v - 2621440LL) * 4;
    float4 f = *(const float4*)(Whh + fi);
    bf16x4 o; o.x = (bf16_t)f.x; o.y = (bf16_t)f.y; o.z = (bf16_t)f.z; o.w = (bf16_t)f.w;
    *(bf16x4*)(whhbf + fi) = o;
  } else if (v < 3678208LL) {                // h0: 32768 floats -> htr slot 0 (slab layout)
    long long fi = (v - 3670016LL) * 4;
    int b = (int)(fi >> 10), c = (int)(fi & 1023);
    float4 f = *(const float4*)(h0 + fi);
    bf16x4 o; o.x = (bf16_t)f.x; o.y = (bf16_t)f.y; o.z = (bf16_t)f.z; o.w = (bf16_t)f.w;
    *(bf16x4*)(htr + (long long)(c >> 4) * 512 + b * 16 + (c & 15)) = o;
  } else if (v < 5775360LL) {                // canary fill slots 1..512 (16.78M elems)
    long long idx = v - 3678208LL;           // 2097152 threads * 8 elems
    *(int4*)(htr + 32768LL + idx * 8) = make_int4(-1, -1, -1, -1);
  }
}

// ---------------------------------------------------------------------------
// Kernel 2: x_proj = X(bf16, rows t*32+b) @ W_ih^T + b_ih + b_hh  -> bf16
// r13: global_load_lds width-16 staging (async direct-to-LDS), pre-swizzled
// global source + linear LDS dest (layout unchanged from the reg-staged
// version, so the MFMA-side swizzled reads are identical).
// ---------------------------------------------------------------------------
__device__ __forceinline__ void gload_lds16(const void* g, void* l) {
  __builtin_amdgcn_global_load_lds(
      (const __attribute__((address_space(1))) unsigned int*)g,
      (__attribute__((address_space(3))) unsigned int*)l, 16, 0, 0);
}

__global__ __launch_bounds__(256) void xproj_gemm(
    const bf16_t* __restrict__ Xb, const bf16_t* __restrict__ Wb,
    const float* __restrict__ bih, const float* __restrict__ bhh,
    bf16_t* __restrict__ XP)
{
  __shared__ bf16_t As[128*64];
  __shared__ bf16_t Bs[128*64];
  const int tid = threadIdx.x;
  const int lane = tid & 63, wave = tid >> 6;
  const int mhalf = wave & 1, nhalf = wave >> 1;
  const int l31 = lane & 31, khi = lane >> 5;
  const int m0 = blockIdx.x * 128, n0 = blockIdx.y * 128;

  f32x16 acc[2][2] = {};

  for (int kb = 0; kb < 8; ++kb) {
    const int k0 = kb * 64;
    __syncthreads();
#pragma unroll
    for (int j = 0; j < 4; ++j) {
      int cid = j * 256 + tid;
      int r = cid >> 3, bs = cid & 7;
      int bb = bs ^ (r & 7);
      // async global->LDS, 16B/lane; LDS dest linear in cid (wave-uniform
      // base + lane*16), swizzle applied on the global source column.
      gload_lds16(Xb + (long long)(m0 + r) * 512 + k0 + bb * 8, As + cid * 8);
      gload_lds16(Wb + (long long)(n0 + r) * 512 + k0 + bb * 8, Bs + cid * 8);
    }
    __syncthreads();   // compiler drains vmcnt before s_barrier
#pragma unroll
    for (int ks = 0; ks < 4; ++ks) {
      int blk = ks * 2 + khi;
      bf16x8 af[2], bfr[2];
#pragma unroll
      for (int mt = 0; mt < 2; ++mt) {
        int r = mhalf * 64 + mt * 32 + l31;
        af[mt] = *(const bf16x8*)(As + (r * 8 + (blk ^ (r & 7))) * 8);
      }
#pragma unroll
      for (int nt = 0; nt < 2; ++nt) {
        int r = nhalf * 64 + nt * 32 + l31;
        bfr[nt] = *(const bf16x8*)(Bs + (r * 8 + (blk ^ (r & 7))) * 8);
      }
#pragma unroll
      for (int mt = 0; mt < 2; ++mt)
#pragma unroll
        for (int nt = 0; nt < 2; ++nt)
          acc[mt][nt] = __builtin_amdgcn_mfma_f32_32x32x16_bf16(af[mt], bfr[nt], acc[mt][nt], 0, 0, 0);
    }
  }
#pragma unroll
  for (int nt = 0; nt < 2; ++nt) {
    int ng = n0 + nhalf * 64 + nt * 32 + l31;
    float bias = bih[ng] + bhh[ng];
#pragma unroll
    for (int mt = 0; mt < 2; ++mt) {
#pragma unroll
      for (int r = 0; r < 16; ++r) {
        int row = (r & 3) + 8 * (r >> 2) + 4 * khi;
        long long mg = m0 + mhalf * 64 + mt * 32 + row;   // = t*32 + b
        XP[mg * 4096 + ng] = (bf16_t)(acc[mt][nt][r] + bias);
      }
    }
  }
}

// ---------------------------------------------------------------------------
// Kernel 3: persistent LSTM recurrence, canary-validated data-poll sync.
// FROZEN r12 state (latency floor): 64 WGs x 256 threads; wave = K-quarter;
// lean bulk poll + v_max3 validate + s_sleep(1) failure backoff; float2 gL
// exchange (0 bank conflicts); rcpf gates; OUT-before-poll.
// ---------------------------------------------------------------------------
__device__ __forceinline__ float sigf(float x) {
  return __builtin_amdgcn_rcpf(1.0f + __expf(-x));
}
__device__ __forceinline__ float tanhfast(float x) {
  float e = __expf(-2.0f * fabsf(x));
  float t = (1.0f - e) * __builtin_amdgcn_rcpf(1.0f + e);
  return copysignf(t, x);
}
__device__ __forceinline__ unsigned umax2(unsigned a, unsigned b) { return a > b ? a : b; }
__device__ __forceinline__ unsigned umax3(unsigned a, unsigned b, unsigned c) {
  unsigned d;
  asm("v_max3_u32 %0, %1, %2, %3" : "=v"(d) : "v"(a), "v"(b), "v"(c));
  return d;
}

#define LD16(dst, ptr, OFF) \
  asm volatile("global_load_dwordx4 %0, %1, off offset:" OFF " sc0 sc1" \
               : "=v"(dst) : "v"(ptr) : "memory")

__global__ __launch_bounds__(256, 1) void lstm_rec(
    const bf16_t* __restrict__ Whh_b, const bf16_t* __restrict__ XP,
    const float* __restrict__ c0, float* __restrict__ OUT,
    bf16_t* __restrict__ HTR)
{
  const int tid = threadIdx.x;
  const int lane = tid & 63, wave = tid >> 6;
  const int kq = wave;                              // K-quarter 0..3
  const int wg = blockIdx.x;
  const int l31 = lane & 31, khi = lane >> 5;

  // --- preload W_hh fragments for BOTH n-tiles of my K-quarter ---
  const int g0row = (l31 >> 4) * 1024 + wg * 16 + (l31 & 15);
  const int g1row = (2 + (l31 >> 4)) * 1024 + wg * 16 + (l31 & 15);
  const int kqb = kq * 256 + khi * 8;               // k-base of my quarter
  bf16x8 w0[16], w1[16];
#pragma unroll
  for (int s = 0; s < 16; ++s) {
    w0[s] = *(const bf16x8*)(Whh_b + (long long)g0row * 1024 + kqb + s * 16);
    w1[s] = *(const bf16x8*)(Whh_b + (long long)g1row * 1024 + kqb + s * 16);
  }

  // A-fragment byte base: slab (kq*16+s), row l31, cols khi*8..+8
  const char* abase = (const char*)HTR + kq * 16384 + l31 * 32 + khi * 16;

  // gate exchange LDS, float2-packed: gL2[parity][kq][m][col] where
  //   col<16: (i_c, g_c), col>=16: (f_{c-16}, o_{c-16})
  __shared__ float2 gL2[2][4][32][33];   // 33-pad, 67.6KB total

  const int m_e = tid >> 3;
  const int jp = (tid & 7) * 2;          // owned col pair (jp, jp+1), 0..14
  float cr0 = c0[m_e * 1024 + wg * 16 + jp];
  float cr1 = c0[m_e * 1024 + wg * 16 + jp + 1];

  // prefetch xp for t=0
  float xp[4][2];
  {
    const bf16_t* xpb = XP + (long long)m_e * 4096 + wg * 16 + jp;
#pragma unroll
    for (int g = 0; g < 4; ++g) {
      bf16x2 v = *(const bf16x2*)(xpb + g * 1024);
      xp[g][0] = (float)v.x; xp[g][1] = (float)v.y;
    }
  }

  float po0 = 0.0f, po1 = 0.0f;   // deferred OUT values (step t-1)

  for (int t = 0; t < 512; ++t) {
    // ---- deferred OUT store for step t-1 (issue BEFORE poll; ack overlaps) ----
    if (t > 0)
      *(float2*)(OUT + ((long long)m_e * 512 + (t - 1)) * 1024 + wg * 16 + jp) =
          make_float2(po0, po1);

    // ---- bulk-load + canary-validate the 16 slabs of my K-quarter ----
    const char* p0 = abase + ((long long)t << 16);
    const char* p1 = p0 + 4096;
    const char* p2 = p0 + 8192;
    const char* p3 = p0 + 12288;
    i32x4 a[16];
    for (;;) {
      LD16(a[0],  p0, "0"); LD16(a[1],  p0, "1024"); LD16(a[2],  p0, "2048"); LD16(a[3],  p0, "3072");
      LD16(a[4],  p1, "0"); LD16(a[5],  p1, "1024"); LD16(a[6],  p1, "2048"); LD16(a[7],  p1, "3072");
      LD16(a[8],  p2, "0"); LD16(a[9],  p2, "1024"); LD16(a[10], p2, "2048"); LD16(a[11], p2, "3072");
      LD16(a[12], p3, "0"); LD16(a[13], p3, "1024"); LD16(a[14], p3, "2048"); LD16(a[15], p3, "3072");
      asm volatile("s_waitcnt vmcnt(0)" ::: "memory");
      __builtin_amdgcn_sched_barrier(0);
      // v_max3 tree: 40 ops
      unsigned pv[16];
#pragma unroll
      for (int s = 0; s < 16; ++s)
        pv[s] = umax2(umax3((unsigned)a[s][0], (unsigned)a[s][1],
                            (unsigned)a[s][2]), (unsigned)a[s][3]);
      unsigned q0 = umax3(pv[0],  pv[1],  pv[2]);
      unsigned q1 = umax3(pv[3],  pv[4],  pv[5]);
      unsigned q2 = umax3(pv[6],  pv[7],  pv[8]);
      unsigned q3 = umax3(pv[9],  pv[10], pv[11]);
      unsigned q4 = umax3(pv[12], pv[13], pv[14]);
      unsigned r0 = umax3(q0, q1, q2);
      unsigned r1 = umax3(q3, q4, pv[15]);
      unsigned mx = umax2(r0, r1);
      if (!__any((int)(mx == 0xFFFFFFFFu))) break;
      __builtin_amdgcn_s_sleep(1);   // failure path only: thin the re-issue storm
    }

    // ---- gates partial for my K-quarter, both n-tiles ----
    f32x16 acc0 = {}, acc1 = {};
#pragma unroll
    for (int s = 0; s < 16; ++s) {
      bf16x8 af = __builtin_bit_cast(bf16x8, a[s]);
      acc0 = __builtin_amdgcn_mfma_f32_32x32x16_bf16(af, w0[s], acc0, 0, 0, 0);
      acc1 = __builtin_amdgcn_mfma_f32_32x32x16_bf16(af, w1[s], acc1, 0, 0, 0);
    }

    float2 (*gp)[33] = gL2[t & 1][kq];
#pragma unroll
    for (int r = 0; r < 16; ++r) {
      int mm = (r & 3) + 8 * (r >> 2) + 4 * khi;
      gp[mm][l31] = make_float2(acc0[r], acc1[r]);   // (i|f, g|o) pair
    }
    __syncthreads();   // single barrier per step (gL parity-double-buffered)

    // ---- elementwise LSTM cell for (m_e, jp..jp+1), c in registers ----
    float2 (*ge)[32][33] = gL2[t & 1];
    float hv[2];
    {
      float ir = xp[0][0], fr = xp[1][0], gr = xp[2][0], orr = xp[3][0];
#pragma unroll
      for (int k = 0; k < 4; ++k) {
        float2 ig = ge[k][m_e][jp];
        float2 fo = ge[k][m_e][16 + jp];
        ir += ig.x; gr += ig.y; fr += fo.x; orr += fo.y;
      }
      float c = sigf(fr) * cr0 + sigf(ir) * tanhfast(gr);
      cr0 = c;
      hv[0] = sigf(orr) * tanhfast(c);
    }
    {
      float ir = xp[0][1], fr = xp[1][1], gr = xp[2][1], orr = xp[3][1];
#pragma unroll
      for (int k = 0; k < 4; ++k) {
        float2 ig = ge[k][m_e][jp + 1];
        float2 fo = ge[k][m_e][17 + jp];
        ir += ig.x; gr += ig.y; fr += fo.x; orr += fo.y;
      }
      float c = sigf(fr) * cr1 + sigf(ir) * tanhfast(gr);
      cr1 = c;
      hv[1] = sigf(orr) * tanhfast(c);
    }

    // ---- publish h: sc1 store to LLC, fire-and-forget (data IS the flag) ----
    {
      bf16x2 h2; h2.x = (bf16_t)hv[0]; h2.y = (bf16_t)hv[1];
      unsigned int u = __builtin_bit_cast(unsigned int, h2);
      unsigned int* dst = (unsigned int*)(HTR + (long long)(t + 1) * 32768 +
                                          (long long)wg * 512 + m_e * 16 + jp);
      __hip_atomic_store(dst, u, __ATOMIC_RELAXED, __HIP_MEMORY_SCOPE_AGENT);
    }
    po0 = hv[0]; po1 = hv[1];

    // ---- next-step xp prefetch ----
    if (t < 511) {
      const bf16_t* xpb = XP + ((long long)(t + 1) * 32 + m_e) * 4096 + wg * 16 + jp;
#pragma unroll
      for (int g = 0; g < 4; ++g) {
        bf16x2 v = *(const bf16x2*)(xpb + g * 1024);
        xp[g][0] = (float)v.x; xp[g][1] = (float)v.y;
      }
    }
  }
  // final OUT store (t = 511)
  *(float2*)(OUT + ((long long)m_e * 512 + 511) * 1024 + wg * 16 + jp) =
      make_float2(po0, po1);
}

// ---------------------------------------------------------------------------
extern "C" void kernel_launch(void* const* d_in, const int* in_sizes, int n_in,
                              void* d_out, int out_size, void* d_ws, size_t ws_size,
                              hipStream_t stream)
{
  const float* x   = (const float*)d_in[0];
  const float* h0  = (const float*)d_in[1];
  const float* c0  = (const float*)d_in[2];
  const float* Wih = (const float*)d_in[3];
  const float* Whh = (const float*)d_in[4];
  const float* bih = (const float*)d_in[5];
  const float* bhh = (const float*)d_in[6];
  float* out = (float*)d_out;

  char* ws = (char*)d_ws;
  bf16_t* xbf   = (bf16_t*)(ws + OFF_XBF);
  bf16_t* wihbf = (bf16_t*)(ws + OFF_WIH);
  bf16_t* whhbf = (bf16_t*)(ws + OFF_WHH);
  bf16_t* xproj = (bf16_t*)(ws + OFF_XPROJ);
  bf16_t* htr   = (bf16_t*)(ws + OFF_HTR);

  convert_pack<<<22560, 256, 0, stream>>>(x, h0, Wih, Whh, xbf, wihbf, whhbf, htr);
  xproj_gemm<<<dim3(128, 32), 256, 0, stream>>>(xbf, wihbf, bih, bhh, xproj);
  lstm_rec<<<64, 256, 0, stream>>>(whhbf, xproj, c0, out, htr);
}